// Round 5
// baseline (321.831 us; speedup 1.0000x reference)
//
#include <hip/hip_runtime.h>
#include <hip/hip_cooperative_groups.h>
#include <math.h>

namespace cg = cooperative_groups;

#define NB 8        // batches
#define NN 4096     // nodes
#define NE 131072   // edges
#define NF 64       // features
#define CAP 256     // bucket capacity per node (degree ~Poisson(32), max ~60)
#define PCAP 128    // per-wave LDS edge cache capacity
#define LRELU_ALPHA 0.2f

// float -> bf16 (RNE)
static __device__ __forceinline__ ushort bf16r(float x) {
  uint u = __float_as_uint(x);
  return (ushort)((u + 0x7fffu + ((u >> 16) & 1u)) >> 16);
}

// ---------------------------------------------------------------------------
// Single cooperative kernel, 512 blocks x 256 threads (2 blocks/CU resident).
// Phase A: zero cnt.
// Phase B: (all blocks) gemm Wh=h@W (bf16) + scores s1/s2, then bucket-append
//          edges by src.
// Phase C: aggregation, persistent: block -> batch (blk&7, XCD-pinned),
//          each of 4 waves handles 16 nodes sequentially.
// grid.sync() + __threadfence() between phases (cross-XCD visibility).
// ---------------------------------------------------------------------------
__global__ __launch_bounds__(256, 2) void gat_fused_kernel(
    const float* __restrict__ h, const float* __restrict__ W,
    const float* __restrict__ a, const int* __restrict__ src,
    const int* __restrict__ dst, const float* __restrict__ ew,
    ushort* __restrict__ Whb, float* __restrict__ ssrc,
    float* __restrict__ sdst, int* __restrict__ cnt,
    int2* __restrict__ bucket, float* __restrict__ out) {
  cg::grid_group grid = cg::this_grid();
  __shared__ int2 pex[4][PCAP];  // 4 KiB, wave-private rows
  int tid = threadIdx.x;
  int blk = blockIdx.x;
  int f = tid & 63;
  int w = tid >> 6;  // wave within block [0,4)

  // ---- Phase A: zero cnt (512 blocks x 8 = 4096)
  if (tid < 8) cnt[blk * 8 + tid] = 0;
  __threadfence();
  grid.sync();

  // ---- Phase B1: gemm. wave gw = blk*4+w in [0,2048), 16 rows each.
  {
    float Wc[64];
#pragma unroll
    for (int k = 0; k < 64; k++) Wc[k] = W[k * 64 + f];
    float A1 = a[f];
    float A2 = a[64 + f];
    int row0 = __builtin_amdgcn_readfirstlane(blk * 4 + w) * 16;
#pragma unroll 2
    for (int r = 0; r < 16; r++) {
      int row = row0 + r;  // wave-uniform -> h loads via scalar cache
      const float* hr = h + (size_t)row * NF;
      float ac0 = 0.f, ac1 = 0.f, ac2 = 0.f, ac3 = 0.f;
#pragma unroll
      for (int k = 0; k < 64; k += 4) {
        ac0 += hr[k] * Wc[k];
        ac1 += hr[k + 1] * Wc[k + 1];
        ac2 += hr[k + 2] * Wc[k + 2];
        ac3 += hr[k + 3] * Wc[k + 3];
      }
      float acc = (ac0 + ac1) + (ac2 + ac3);
      Whb[(size_t)row * NF + f] = bf16r(acc);
      float v1 = acc * A1;
      float v2 = acc * A2;
#pragma unroll
      for (int off = 1; off < 64; off <<= 1) {
        v1 += __shfl_xor(v1, off);
        v2 += __shfl_xor(v2, off);
      }
      if (f == 0) ssrc[row] = v1;
      if (f == 32) sdst[row] = v2;
    }
  }
  // ---- Phase B2: bucket-append. One edge per thread (512*256 = NE).
  {
    int e = blk * 256 + tid;
    int s = src[e];
    int d = dst[e];
    float wt = ew[e];
    int p = atomicAdd(&cnt[s], 1);
    if (p < CAP) bucket[s * CAP + p] = make_int2(d, __float_as_int(wt));
  }
  __threadfence();
  grid.sync();

  // ---- Phase C: aggregation. b = blk&7 (XCD-pinned), j = blk>>3 in [0,64).
  {
    int b = blk & 7;
    int j = blk >> 3;
    const float* sdB = sdst + b * NN;
    const ushort* WhB = Whb + (size_t)b * NN * NF;
    for (int it = 0; it < 16; it++) {
      int n = j * 64 + it * 4 + w;
      int cntn = min(cnt[n], PCAP);
      float ss = ssrc[b * NN + n];
      const int2* bkt = bucket + n * CAP;
      float den = 0.f;
      for (int i = f; i < cntn; i += 64) {
        int2 e = bkt[i];
        float x = ss + sdB[e.x];
        x = (x > 0.f) ? x : LRELU_ALPHA * x;
        x *= __int_as_float(e.y);
        float v = __expf(x);
        pex[w][i] = make_int2(e.x, __float_as_int(v));
        den += v;
      }
#pragma unroll
      for (int off = 1; off < 64; off <<= 1) den += __shfl_xor(den, off);

      const int4* pv = (const int4*)&pex[w][0];
      float acc0 = 0.f, acc1 = 0.f, acc2 = 0.f, acc3 = 0.f;
      float acc4 = 0.f, acc5 = 0.f, acc6 = 0.f, acc7 = 0.f;
      int i = 0;
      for (; i + 8 <= cntn; i += 8) {
        int4 q0 = pv[(i >> 1) + 0];
        int4 q1 = pv[(i >> 1) + 1];
        int4 q2 = pv[(i >> 1) + 2];
        int4 q3 = pv[(i >> 1) + 3];
        float w0 = __uint_as_float(((uint)WhB[(q0.x << 6) + f]) << 16);
        float w1 = __uint_as_float(((uint)WhB[(q0.z << 6) + f]) << 16);
        float w2 = __uint_as_float(((uint)WhB[(q1.x << 6) + f]) << 16);
        float w3 = __uint_as_float(((uint)WhB[(q1.z << 6) + f]) << 16);
        float w4 = __uint_as_float(((uint)WhB[(q2.x << 6) + f]) << 16);
        float w5 = __uint_as_float(((uint)WhB[(q2.z << 6) + f]) << 16);
        float w6 = __uint_as_float(((uint)WhB[(q3.x << 6) + f]) << 16);
        float w7 = __uint_as_float(((uint)WhB[(q3.z << 6) + f]) << 16);
        acc0 += __int_as_float(q0.y) * w0;
        acc1 += __int_as_float(q0.w) * w1;
        acc2 += __int_as_float(q1.y) * w2;
        acc3 += __int_as_float(q1.w) * w3;
        acc4 += __int_as_float(q2.y) * w4;
        acc5 += __int_as_float(q2.w) * w5;
        acc6 += __int_as_float(q3.y) * w6;
        acc7 += __int_as_float(q3.w) * w7;
      }
      for (; i < cntn; i++) {
        int2 p = pex[w][i];
        acc0 += __int_as_float(p.y) *
                __uint_as_float(((uint)WhB[(p.x << 6) + f]) << 16);
      }
      float accs =
          ((acc0 + acc1) + (acc2 + acc3)) + ((acc4 + acc5) + (acc6 + acc7));
      float hp = (cntn > 0) ? accs / den : 0.f;
      out[((size_t)(b * NN + n)) * NF + f] = (hp > 0.f) ? hp : expm1f(hp);
    }
  }
}

// ---------------------------------------------------------------------------
extern "C" void kernel_launch(void* const* d_in, const int* in_sizes, int n_in,
                              void* d_out, int out_size, void* d_ws,
                              size_t ws_size, hipStream_t stream) {
  const float* h = (const float*)d_in[0];
  const int* edge_index = (const int*)d_in[1];
  const float* ew = (const float*)d_in[2];
  const float* W = (const float*)d_in[3];
  const float* a = (const float*)d_in[4];
  float* out = (float*)d_out;

  const int* src = edge_index;       // edge_index[0, :]
  const int* dst = edge_index + NE;  // edge_index[1, :]

  // Workspace layout (16B-aligned chunks):
  uint8_t* ws = (uint8_t*)d_ws;
  ushort* Whb = (ushort*)ws;                 // 4 MiB  (B*N*F bf16)
  float* ssrc = (float*)(ws + 4194304);      // 128 KiB
  float* sdst = (float*)(ws + 4325376);      // 128 KiB
  int* cnt = (int*)(ws + 4456448);           // 16 KiB
  int2* bucket = (int2*)(ws + 4472832);      // 8 MiB  (N*CAP*8B)
  // total ~12.3 MiB

  void* args[] = {(void*)&h,    (void*)&W,    (void*)&a,   (void*)&src,
                  (void*)&dst,  (void*)&ew,   (void*)&Whb, (void*)&ssrc,
                  (void*)&sdst, (void*)&cnt,  (void*)&bucket, (void*)&out};
  hipLaunchCooperativeKernel((void*)gat_fused_kernel, dim3(512), dim3(256),
                             args, 0, stream);
}

// Round 6
// 118.207 us; speedup vs baseline: 2.7226x; 2.7226x over previous
//
#include <hip/hip_runtime.h>
#include <math.h>

#define NB 8        // batches
#define NN 4096     // nodes
#define NE 131072   // edges
#define NF 64       // features
#define CAP 256     // bucket capacity per node (degree ~Poisson(32), max ~60)
#define PCAP 128    // per-wave LDS edge cache capacity
#define LRELU_ALPHA 0.2f

// float -> bf16 (RNE)
static __device__ __forceinline__ ushort bf16r(float x) {
  uint u = __float_as_uint(x);
  return (ushort)((u + 0x7fffu + ((u >> 16) & 1u)) >> 16);
}

// ---------------------------------------------------------------------------
// K1 (fused, independent halves):
//   blocks [0,512):    Wh(bf16) = h@W with W columns register-resident.
//                      Wave = 16 rows; lane = output feature. Row loads of h
//                      are wave-uniform (scalar cache). Scores s1/s2 via
//                      fp32 butterfly reduction.
//   blocks [512,1024): bucket-append edges by src: bucket[s*CAP+p]=(dst,w)
// ---------------------------------------------------------------------------
__global__ __launch_bounds__(256) void fused_gemm_append_kernel(
    const float* __restrict__ h, const float* __restrict__ W,
    const float* __restrict__ a, const int* __restrict__ src,
    const int* __restrict__ dst, const float* __restrict__ ew,
    ushort* __restrict__ Whb, float* __restrict__ ssrc,
    float* __restrict__ sdst, int* __restrict__ cnt,
    int2* __restrict__ bucket) {
  int tid = threadIdx.x;
  int blk = blockIdx.x;
  if (blk >= 512) {
    int e = (blk - 512) * 256 + tid;
    int s = src[e];
    int d = dst[e];
    float w = ew[e];
    int p = atomicAdd(&cnt[s], 1);
    if (p < CAP) bucket[s * CAP + p] = make_int2(d, __float_as_int(w));
    return;
  }
  int f = tid & 63;
  int wave = blk * 4 + (tid >> 6);  // 0..2047, 16 rows each
  // W column f -> registers (coalesced loads)
  float Wc[64];
#pragma unroll
  for (int k = 0; k < 64; k++) Wc[k] = W[k * 64 + f];
  float A1 = a[f];
  float A2 = a[64 + f];

  int row0 = __builtin_amdgcn_readfirstlane(wave) * 16;
#pragma unroll 2
  for (int r = 0; r < 16; r++) {
    int row = row0 + r;  // uniform -> h loads go to scalar cache
    const float* hr = h + (size_t)row * NF;
    float ac0 = 0.f, ac1 = 0.f, ac2 = 0.f, ac3 = 0.f;
#pragma unroll
    for (int k = 0; k < 64; k += 4) {
      ac0 += hr[k] * Wc[k];
      ac1 += hr[k + 1] * Wc[k + 1];
      ac2 += hr[k + 2] * Wc[k + 2];
      ac3 += hr[k + 3] * Wc[k + 3];
    }
    float acc = (ac0 + ac1) + (ac2 + ac3);
    Whb[(size_t)row * NF + f] = bf16r(acc);
    float v1 = acc * A1;
    float v2 = acc * A2;
#pragma unroll
    for (int off = 1; off < 64; off <<= 1) {
      v1 += __shfl_xor(v1, off);
      v2 += __shfl_xor(v2, off);
    }
    if (f == 0) ssrc[row] = v1;
    if (f == 32) sdst[row] = v2;
  }
}

// ---------------------------------------------------------------------------
// K2: aggregation, batch-per-block for XCD/L2 locality.
// Block = (batch = blk&7, node group = blk>>3); wave = node; lane = feature.
// Phase 1: exv per edge lane-parallel, stash (dst,exv) in wave-private LDS.
// Phase 2: int4 LDS reads (2 edges/read), 8 outstanding ushort gathers.
// No __syncthreads anywhere.
// ---------------------------------------------------------------------------
__global__ __launch_bounds__(512) void agg_kernel(
    const ushort* __restrict__ Whb, const float* __restrict__ ssrc,
    const float* __restrict__ sdst, const int* __restrict__ cnt,
    const int2* __restrict__ bucket, float* __restrict__ out) {
  __shared__ int2 pex[8][PCAP];  // 8 KiB, wave-private rows
  int blk = blockIdx.x;
  int b = blk & 7;
  int g = blk >> 3;
  int tid = threadIdx.x;
  int w = tid >> 6;  // wave -> node within group
  int f = tid & 63;
  int n = g * 8 + w;

  int cntn = min(cnt[n], PCAP);
  float ss = ssrc[b * NN + n];
  const float* sdB = sdst + b * NN;
  const int2* bkt = bucket + n * CAP;
  float den = 0.f;
  for (int i = f; i < cntn; i += 64) {
    int2 e = bkt[i];
    float x = ss + sdB[e.x];
    x = (x > 0.f) ? x : LRELU_ALPHA * x;
    x *= __int_as_float(e.y);
    float v = __expf(x);
    pex[w][i] = make_int2(e.x, __float_as_int(v));
    den += v;
  }
#pragma unroll
  for (int off = 1; off < 64; off <<= 1) den += __shfl_xor(den, off);

  const ushort* WhB = Whb + (size_t)b * NN * NF;
  const int4* pv = (const int4*)&pex[w][0];
  float acc0 = 0.f, acc1 = 0.f, acc2 = 0.f, acc3 = 0.f;
  float acc4 = 0.f, acc5 = 0.f, acc6 = 0.f, acc7 = 0.f;
  int i = 0;
  for (; i + 8 <= cntn; i += 8) {
    int4 q0 = pv[(i >> 1) + 0];
    int4 q1 = pv[(i >> 1) + 1];
    int4 q2 = pv[(i >> 1) + 2];
    int4 q3 = pv[(i >> 1) + 3];
    float w0 = __uint_as_float(((uint)WhB[(q0.x << 6) + f]) << 16);
    float w1 = __uint_as_float(((uint)WhB[(q0.z << 6) + f]) << 16);
    float w2 = __uint_as_float(((uint)WhB[(q1.x << 6) + f]) << 16);
    float w3 = __uint_as_float(((uint)WhB[(q1.z << 6) + f]) << 16);
    float w4 = __uint_as_float(((uint)WhB[(q2.x << 6) + f]) << 16);
    float w5 = __uint_as_float(((uint)WhB[(q2.z << 6) + f]) << 16);
    float w6 = __uint_as_float(((uint)WhB[(q3.x << 6) + f]) << 16);
    float w7 = __uint_as_float(((uint)WhB[(q3.z << 6) + f]) << 16);
    acc0 += __int_as_float(q0.y) * w0;
    acc1 += __int_as_float(q0.w) * w1;
    acc2 += __int_as_float(q1.y) * w2;
    acc3 += __int_as_float(q1.w) * w3;
    acc4 += __int_as_float(q2.y) * w4;
    acc5 += __int_as_float(q2.w) * w5;
    acc6 += __int_as_float(q3.y) * w6;
    acc7 += __int_as_float(q3.w) * w7;
  }
  for (; i < cntn; i++) {
    int2 p = pex[w][i];
    acc0 += __int_as_float(p.y) *
            __uint_as_float(((uint)WhB[(p.x << 6) + f]) << 16);
  }
  float accs = ((acc0 + acc1) + (acc2 + acc3)) + ((acc4 + acc5) + (acc6 + acc7));
  float hp = (cntn > 0) ? accs / den : 0.f;
  out[((size_t)(b * NN + n)) * NF + f] = (hp > 0.f) ? hp : expm1f(hp);
}

// ---------------------------------------------------------------------------
extern "C" void kernel_launch(void* const* d_in, const int* in_sizes, int n_in,
                              void* d_out, int out_size, void* d_ws,
                              size_t ws_size, hipStream_t stream) {
  const float* h = (const float*)d_in[0];
  const int* edge_index = (const int*)d_in[1];
  const float* ew = (const float*)d_in[2];
  const float* W = (const float*)d_in[3];
  const float* a = (const float*)d_in[4];
  float* out = (float*)d_out;

  const int* src = edge_index;       // edge_index[0, :]
  const int* dst = edge_index + NE;  // edge_index[1, :]

  // Workspace layout (16B-aligned chunks):
  uint8_t* ws = (uint8_t*)d_ws;
  ushort* Whb = (ushort*)ws;                 // 4 MiB  (B*N*F bf16)
  float* ssrc = (float*)(ws + 4194304);      // 128 KiB
  float* sdst = (float*)(ws + 4325376);      // 128 KiB
  int* cnt = (int*)(ws + 4456448);           // 16 KiB
  int2* bucket = (int2*)(ws + 4472832);      // 8 MiB  (N*CAP*8B)
  // total ~12.3 MiB

  hipMemsetAsync(cnt, 0, NN * sizeof(int), stream);
  fused_gemm_append_kernel<<<1024, 256, 0, stream>>>(h, W, a, src, dst, ew,
                                                     Whb, ssrc, sdst, cnt,
                                                     bucket);
  agg_kernel<<<NN, 512, 0, stream>>>(Whb, ssrc, sdst, cnt, bucket, out);
}